// Round 3
// baseline (420.066 us; speedup 1.0000x reference)
//
#include <hip/hip_runtime.h>
#include <stdint.h>

// Problem constants: B=32, H=8, N=257, D=64, DIM=512
#define TOK 8224          // B*N
#define OUT0_OFF 0ull
#define WB_OFF   4210688ull
#define WA_OFF   21119232ull

typedef short short8 __attribute__((ext_vector_type(8)));
typedef float floatx4 __attribute__((ext_vector_type(4)));

__device__ __forceinline__ unsigned short f2bf(float f){
  union { float f; uint32_t u; } v; v.f = f;
  uint32_t u = v.u;
  uint32_t r = (u + 0x7FFFu + ((u >> 16) & 1u)) >> 16;  // RNE
  return (unsigned short)r;
}

// ---- JAX Threefry-2x32 with arbitrary key ----
__device__ __forceinline__ void threefry(uint32_t k0, uint32_t k1, uint32_t c0, uint32_t c1,
                                         uint32_t& o0, uint32_t& o1){
  const uint32_t ks2 = k0 ^ k1 ^ 0x1BD11BDAu;
  uint32_t x0 = c0 + k0, x1 = c1 + k1;
#define TF_R4(a,b,c,d) \
  x0+=x1; x1=(x1<<(a))|(x1>>(32-(a))); x1^=x0; \
  x0+=x1; x1=(x1<<(b))|(x1>>(32-(b))); x1^=x0; \
  x0+=x1; x1=(x1<<(c))|(x1>>(32-(c))); x1^=x0; \
  x0+=x1; x1=(x1<<(d))|(x1>>(32-(d))); x1^=x0;
  TF_R4(13,15,26,6)  x0+=k1;  x1+=ks2+1u;
  TF_R4(17,29,16,24) x0+=ks2; x1+=k0+2u;
  TF_R4(13,15,26,6)  x0+=k0;  x1+=k1+3u;
  TF_R4(17,29,16,24) x0+=k1;  x1+=ks2+4u;
  TF_R4(13,15,26,6)  x0+=ks2; x1+=k0+5u;
#undef TF_R4
  o0 = x0; o1 = x1;
}

// ---- Kernel A: noise + per-batch mask normalization. grid(32) x 256 ----
// JAX >= 0.4.36 default: threefry_partitionable=True.
//   split(key) [foldlike]: key_i = threefry(key, (0, i)) full output pair
//   random_bits(k, 32, shape): elem i -> threefry(k, (hi32(i), lo32(i))), bits = out0 ^ out1
// randint(key(42),(32,16,16),1,128):
//   k1 = threefry((0,42),(0,0)); k2 = threefry((0,42),(0,1))
//   hb_i = xor(threefry(k1,(0,i))); lb_i = xor(threefry(k2,(0,i)))
//   multiplier = (2^16 % 127)^2 % 127 = 16
//   off = ((hb%127)*16 + lb%127) % 127 ; val = 1 + off
__global__ __launch_bounds__(256) void prep_kernel(const int* __restrict__ msk,
                                                   float* __restrict__ mnorm){
  const int b = blockIdx.x, p = threadIdx.x;
  const int i = b*256 + p;
  uint32_t A0, A1, B0, B1;
  threefry(0u, 42u, 0u, 0u, A0, A1);   // k1 = (A0, A1)
  threefry(0u, 42u, 0u, 1u, B0, B1);   // k2 = (B0, B1)
  uint32_t h0, h1, l0, l1;
  threefry(A0, A1, 0u, (uint32_t)i, h0, h1);
  threefry(B0, B1, 0u, (uint32_t)i, l0, l1);
  uint32_t hb = h0 ^ h1;
  uint32_t lb = l0 ^ l1;
  uint32_t off = ((hb % 127u) * 16u + (lb % 127u)) % 127u;
  int mv = msk[i];
  float m = (mv == 0) ? (float)(1u + off) : (float)mv;
  __shared__ float sm[256];
  sm[p] = m; __syncthreads();
  for (int s = 128; s > 0; s >>= 1){
    if (p < s) sm[p] = fmaxf(sm[p], sm[p+s]);
    __syncthreads();
  }
  mnorm[i] = m / sm[0];
}

// ---- Kernel B: QKV GEMM  out[8224,1536] = x[8224,512] @ W[1536,512]^T (bf16 MFMA)
// grid(24, 129), block 256 (4 waves 2x2), tile 64x64, BK=32.
__global__ __launch_bounds__(256) void qkv_gemm(const float* __restrict__ x,
                                                const float* __restrict__ w,
                                                unsigned short* __restrict__ qkv){
  __shared__ unsigned short a_lds[64*40];
  __shared__ unsigned short b_lds[64*40];
  const int bn = blockIdx.x, bm = blockIdx.y;
  const int tid = threadIdx.x;
  const int wave = tid >> 6, lane = tid & 63;
  const int l16 = lane & 15, lq = lane >> 4;
  const int wm = (wave & 1) * 32, wn = (wave >> 1) * 32;
  floatx4 acc[2][2] = {};
  for (int kk = 0; kk < 512; kk += 32){
    #pragma unroll
    for (int i = 0; i < 2; i++){
      int c = tid + i*256;
      int row = c >> 3, c4 = (c & 7) * 4;
      int gm = bm*64 + row; if (gm > 8223) gm = 8223;
      float4 xv = *(const float4*)&x[(size_t)gm*512 + kk + c4];
      ushort4 pa; pa.x = f2bf(xv.x); pa.y = f2bf(xv.y); pa.z = f2bf(xv.z); pa.w = f2bf(xv.w);
      *(ushort4*)&a_lds[row*40 + c4] = pa;
      int gj = bn*64 + row;
      float4 wv = *(const float4*)&w[(size_t)gj*512 + kk + c4];
      ushort4 pb; pb.x = f2bf(wv.x); pb.y = f2bf(wv.y); pb.z = f2bf(wv.z); pb.w = f2bf(wv.w);
      *(ushort4*)&b_lds[row*40 + c4] = pb;
    }
    __syncthreads();
    short8 af[2], bfr[2];
    #pragma unroll
    for (int mi = 0; mi < 2; mi++)
      af[mi] = *(const short8*)&a_lds[(wm + mi*16 + l16)*40 + lq*8];
    #pragma unroll
    for (int ni = 0; ni < 2; ni++)
      bfr[ni] = *(const short8*)&b_lds[(wn + ni*16 + l16)*40 + lq*8];
    #pragma unroll
    for (int mi = 0; mi < 2; mi++)
      #pragma unroll
      for (int ni = 0; ni < 2; ni++)
        acc[mi][ni] = __builtin_amdgcn_mfma_f32_16x16x32_bf16(af[mi], bfr[ni], acc[mi][ni], 0, 0, 0);
    __syncthreads();
  }
  #pragma unroll
  for (int mi = 0; mi < 2; mi++)
    #pragma unroll
    for (int ni = 0; ni < 2; ni++)
      #pragma unroll
      for (int r = 0; r < 4; r++){
        int gm = bm*64 + wm + mi*16 + lq*4 + r;
        if (gm < 8224){
          int gn = bn*64 + wn + ni*16 + l16;
          qkv[(size_t)gm*1536 + gn] = f2bf(acc[mi][ni][r]);
        }
      }
}

// ---- Kernel C: fused retention. grid(5, 256): x=row tile (64 rows), y=(b*8+h).
// LDS: reg1 = k[272][72]u16 (39168B), reused as vT[64][296]u16.
//      reg2 = q[64][72] + pkvT[64][72] (18432B), reused as P-chunk[64][72].
//      mn[256]f + red[64]f. Total 58880 B (dynamic).
__global__ __launch_bounds__(256) void retention_kernel(
    const unsigned short* __restrict__ qkv,
    const float* __restrict__ past_kv,
    const float* __restrict__ mnorm,
    float* __restrict__ out,
    float* __restrict__ partials){
  const int t  = blockIdx.x;
  const int bh = blockIdx.y;
  const int b = bh >> 3, h = bh & 7;
  const int tid = threadIdx.x;
  const int wave = tid >> 6, lane = tid & 63;
  const int l16 = lane & 15, lq = lane >> 4;
  const int rw = wave * 16;

  extern __shared__ unsigned char smem[];
  unsigned short* reg1 = (unsigned short*)smem;
  unsigned short* reg2 = (unsigned short*)(smem + 39168);
  unsigned short* qlds = reg2;
  unsigned short* pk   = reg2 + 64*72;
  float* mn  = (float*)(smem + 39168 + 18432);
  float* red = mn + 256;

  // ---- phase 0: stage k (rows 0..256, pad rows 257..271 zeroed), q tile, 0.125*past_kv^T, mn
  {
    uint32_t* z = (uint32_t*)(reg1 + 257*72);
    for (int i = tid; i < 540; i += 256) z[i] = 0;   // 15 pad rows
  }
  for (int c = tid; c < 257*16; c += 256){
    int row = c >> 4, c4 = (c & 15) * 4;
    ushort4 v = *(const ushort4*)&qkv[(size_t)(b*257 + row)*1536 + 512 + h*64 + c4];
    *(ushort4*)&reg1[row*72 + c4] = v;
  }
  for (int c = tid; c < 64*16; c += 256){
    int row = c >> 4, c4 = (c & 15) * 4;
    int gi0 = t*64 + row; if (gi0 > 256) gi0 = 256;   // clamp (dup row 256; guarded later)
    ushort4 v = *(const ushort4*)&qkv[(size_t)(b*257 + gi0)*1536 + h*64 + c4];
    *(ushort4*)&qlds[row*72 + c4] = v;
  }
  for (int c = tid; c < 64*16; c += 256){
    int d = c >> 4, e4 = (c & 15) * 4;
    float4 v = *(const float4*)&past_kv[(size_t)bh*4096 + d*64 + e4];
    pk[(e4+0)*72 + d] = f2bf(0.125f * v.x);
    pk[(e4+1)*72 + d] = f2bf(0.125f * v.y);
    pk[(e4+2)*72 + d] = f2bf(0.125f * v.z);
    pk[(e4+3)*72 + d] = f2bf(0.125f * v.w);
  }
  mn[tid] = mnorm[b*256 + tid];
  __syncthreads();

  // ---- cross-retention first (so q/pk LDS can be freed): acc2 = q @ (0.125*past_kv)
  floatx4 acc2[4] = {};
  #pragma unroll
  for (int ks = 0; ks < 2; ks++){
    short8 a = *(const short8*)&qlds[(rw + l16)*72 + ks*32 + lq*8];
    #pragma unroll
    for (int ni = 0; ni < 4; ni++){
      short8 bb = *(const short8*)&pk[(ni*16 + l16)*72 + ks*32 + lq*8];
      acc2[ni] = __builtin_amdgcn_mfma_f32_16x16x32_bf16(a, bb, acc2[ni], 0, 0, 0);
    }
  }

  // ---- S = 0.125 * q @ k^T : 16 rows x 272 cols per wave (17 C-frags)
  floatx4 acc[17] = {};
  #pragma unroll
  for (int ks = 0; ks < 2; ks++){
    short8 a = *(const short8*)&qlds[(rw + l16)*72 + ks*32 + lq*8];
    #pragma unroll
    for (int c = 0; c < 17; c++){
      short8 bb = *(const short8*)&reg1[(c*16 + l16)*72 + ks*32 + lq*8];
      acc[c] = __builtin_amdgcn_mfma_f32_16x16x32_bf16(a, bb, acc[c], 0, 0, 0);
    }
  }
  #pragma unroll
  for (int c = 0; c < 17; c++) acc[c] *= 0.125f;

  __syncthreads();   // done reading k (reg1) and q/pk (reg2)

  // ---- re-stage reg1 as vT[e][j] (zero first: pads j>=257 must be 0)
  {
    uint32_t* z = (uint32_t*)reg1;
    for (int i = tid; i < (64*296)/2; i += 256) z[i] = 0;
  }
  __syncthreads();
  for (int c = tid; c < 257*16; c += 256){
    int row = c >> 4, c4 = (c & 15) * 4;
    ushort4 v = *(const ushort4*)&qkv[(size_t)(b*257 + row)*1536 + 1024 + h*64 + c4];
    reg1[(c4+0)*296 + row] = v.x;
    reg1[(c4+1)*296 + row] = v.y;
    reg1[(c4+2)*296 + row] = v.z;
    reg1[(c4+3)*296 + row] = v.w;
  }

  int gi[4]; bool rowok[4];
  #pragma unroll
  for (int r = 0; r < 4; r++){ gi[r] = t*64 + rw + lq*4 + r; rowok[r] = (gi[r] < 257); }

  // ---- weights_before = softmax(S/8): max/sum across 17 frags + 16-lane shuffle group
  float mx[4], sum_[4], inv_[4];
  #pragma unroll
  for (int r = 0; r < 4; r++) mx[r] = -3.0e38f;
  #pragma unroll
  for (int c = 0; c < 17; c++){
    bool jok = (c < 16) || (l16 == 0);
    if (jok){
      #pragma unroll
      for (int r = 0; r < 4; r++) mx[r] = fmaxf(mx[r], acc[c][r]);
    }
  }
  #pragma unroll
  for (int m = 1; m < 16; m <<= 1){
    #pragma unroll
    for (int r = 0; r < 4; r++) mx[r] = fmaxf(mx[r], __shfl_xor(mx[r], m, 64));
  }
  #pragma unroll
  for (int r = 0; r < 4; r++) sum_[r] = 0.f;
  #pragma unroll
  for (int c = 0; c < 17; c++){
    bool jok = (c < 16) || (l16 == 0);
    if (jok){
      #pragma unroll
      for (int r = 0; r < 4; r++) sum_[r] += __expf((acc[c][r] - mx[r]) * 0.125f);
    }
  }
  #pragma unroll
  for (int m = 1; m < 16; m <<= 1){
    #pragma unroll
    for (int r = 0; r < 4; r++) sum_[r] += __shfl_xor(sum_[r], m, 64);
  }
  #pragma unroll
  for (int r = 0; r < 4; r++) inv_[r] = 1.0f / sum_[r];
  {
    const size_t base = WB_OFF + (size_t)bh * 257 * 257;
    #pragma unroll
    for (int c = 0; c < 17; c++){
      int j = c*16 + l16;
      if (j < 257){
        #pragma unroll
        for (int r = 0; r < 4; r++)
          if (rowok[r]) out[base + (size_t)gi[r]*257 + j] = __expf((acc[c][r] - mx[r]) * 0.125f) * inv_[r];
      }
    }
  }

  // ---- apply mask in place: 0 (j>i), 1 (j==i), exp(-5i/256) (j==0), else mn[i-1]*mn[j-1]
  #pragma unroll
  for (int c = 0; c < 17; c++){
    int j = c*16 + l16;
    #pragma unroll
    for (int r = 0; r < 4; r++){
      int ii = gi[r] > 256 ? 256 : gi[r];  // clamp (invalid rows are discarded anyway)
      float mv;
      if (j > ii)       mv = 0.f;
      else if (j == ii) mv = 1.f;
      else if (j == 0)  mv = __expf(-5.f * (float)ii * (1.f/256.f));
      else              mv = mn[ii-1] * mn[j-1];
      acc[c][r] *= mv;
    }
  }

  // ---- weights_after = softmax(masked/8)
  #pragma unroll
  for (int r = 0; r < 4; r++) mx[r] = -3.0e38f;
  #pragma unroll
  for (int c = 0; c < 17; c++){
    bool jok = (c < 16) || (l16 == 0);
    if (jok){
      #pragma unroll
      for (int r = 0; r < 4; r++) mx[r] = fmaxf(mx[r], acc[c][r]);
    }
  }
  #pragma unroll
  for (int m = 1; m < 16; m <<= 1){
    #pragma unroll
    for (int r = 0; r < 4; r++) mx[r] = fmaxf(mx[r], __shfl_xor(mx[r], m, 64));
  }
  #pragma unroll
  for (int r = 0; r < 4; r++) sum_[r] = 0.f;
  #pragma unroll
  for (int c = 0; c < 17; c++){
    bool jok = (c < 16) || (l16 == 0);
    if (jok){
      #pragma unroll
      for (int r = 0; r < 4; r++) sum_[r] += __expf((acc[c][r] - mx[r]) * 0.125f);
    }
  }
  #pragma unroll
  for (int m = 1; m < 16; m <<= 1){
    #pragma unroll
    for (int r = 0; r < 4; r++) sum_[r] += __shfl_xor(sum_[r], m, 64);
  }
  #pragma unroll
  for (int r = 0; r < 4; r++) inv_[r] = 1.0f / sum_[r];
  {
    const size_t base = WA_OFF + (size_t)bh * 257 * 257;
    #pragma unroll
    for (int c = 0; c < 17; c++){
      int j = c*16 + l16;
      if (j < 257){
        #pragma unroll
        for (int r = 0; r < 4; r++)
          if (rowok[r]) out[base + (size_t)gi[r]*257 + j] = __expf((acc[c][r] - mx[r]) * 0.125f) * inv_[r];
      }
    }
  }

  __syncthreads();   // vT ready; all waves ready for P-chunk writes

  // ---- inner = masked @ v, chunked over 64 j-cols through LDS (C-layout -> A-layout)
  unsigned short* p = reg2;
  for (int ch = 0; ch <= t; ch++){
    const int rowb = rw + lq*4;
    #pragma unroll
    for (int fi = 0; fi < 4; fi++){
      int f = ch*4 + fi;
      if (f < 17){
        #pragma unroll
        for (int r = 0; r < 4; r++){
          int j = f*16 + l16;
          p[(rowb + r)*72 + fi*16 + l16] = (j < 257) ? f2bf(acc[f][r]) : (unsigned short)0;
        }
      } else {
        #pragma unroll
        for (int r = 0; r < 4; r++) p[(rowb + r)*72 + fi*16 + l16] = 0;
      }
    }
    __syncthreads();
    const int nks = (ch == 4) ? 1 : 2;   // chunk 4 only has j<=287 nonzero coverage
    for (int ks = 0; ks < nks; ks++){
      short8 a = *(const short8*)&p[(rw + l16)*72 + ks*32 + lq*8];
      #pragma unroll
      for (int ni = 0; ni < 4; ni++){
        short8 bb = *(const short8*)&reg1[(ni*16 + l16)*296 + ch*64 + ks*32 + lq*8];
        acc2[ni] = __builtin_amdgcn_mfma_f32_16x16x32_bf16(a, bb, acc2[ni], 0, 0, 0);
      }
    }
    __syncthreads();
  }

  // ---- r = inner + cross: store (pre-norm) + GroupNorm partial sums
  float ls = 0.f, lss = 0.f;
  #pragma unroll
  for (int ni = 0; ni < 4; ni++)
    #pragma unroll
    for (int r = 0; r < 4; r++)
      if (rowok[r]){
        float v = acc2[ni][r];
        ls += v; lss += v*v;
        out[(size_t)(b*257 + gi[r])*512 + h*64 + ni*16 + l16] = v;
      }
  #pragma unroll
  for (int m = 1; m < 64; m <<= 1){ ls += __shfl_xor(ls, m, 64); lss += __shfl_xor(lss, m, 64); }
  if (lane == 0){ red[wave*2] = ls; red[wave*2 + 1] = lss; }
  __syncthreads();
  if (tid == 0){
    partials[((size_t)bh*5 + t)*2 + 0] = red[0] + red[2] + red[4] + red[6];
    partials[((size_t)bh*5 + t)*2 + 1] = red[1] + red[3] + red[5] + red[7];
  }
}

// ---- Kernel D: GroupNorm finalize in place. grid(256) = (b,h) ----
__global__ __launch_bounds__(256) void norm_kernel(const float* __restrict__ partials,
                                                   const float* __restrict__ gnw,
                                                   const float* __restrict__ gnb,
                                                   float* __restrict__ out){
  const int bh = blockIdx.x, b = bh >> 3, h = bh & 7;
  float s = 0.f, s2 = 0.f;
  #pragma unroll
  for (int tt = 0; tt < 5; tt++){
    s  += partials[(bh*5 + tt)*2 + 0];
    s2 += partials[(bh*5 + tt)*2 + 1];
  }
  const float cnt = 257.f * 64.f;
  float mean = s / cnt;
  float var  = s2 / cnt - mean * mean;
  float isd  = rsqrtf(var + 1e-5f);
  float wsc  = gnw[h] * isd;
  float bia  = gnb[h] - mean * wsc;
  for (int idx = threadIdx.x; idx < 257*64; idx += 256){
    int n = idx >> 6, e = idx & 63;
    size_t off = (size_t)(b*257 + n)*512 + h*64 + e;
    out[off] = out[off] * wsc + bia;
  }
}

extern "C" void kernel_launch(void* const* d_in, const int* in_sizes, int n_in,
                              void* d_out, int out_size, void* d_ws, size_t ws_size,
                              hipStream_t stream){
  (void)in_sizes; (void)n_in; (void)out_size; (void)ws_size;
  const float* x   = (const float*)d_in[0];
  const int*   msk = (const int*)d_in[1];
  const float* w   = (const float*)d_in[2];
  const float* pkv = (const float*)d_in[3];
  const float* gnw = (const float*)d_in[4];
  const float* gnb = (const float*)d_in[5];
  float* out = (float*)d_out;

  unsigned short* qkv = (unsigned short*)d_ws;                      // 8224*1536 bf16 = 25264128 B
  float* mnorm    = (float*)((char*)d_ws + 25264128);               // 32*256 f32
  float* partials = (float*)((char*)d_ws + 25264128 + 32768);       // 256*5*2 f32

  hipLaunchKernelGGL(prep_kernel, dim3(32), dim3(256), 0, stream, msk, mnorm);
  hipLaunchKernelGGL(qkv_gemm, dim3(24, 129), dim3(256), 0, stream, x, w, qkv);
  hipLaunchKernelGGL(retention_kernel, dim3(5, 256), dim3(256), 58880, stream,
                     qkv, pkv, mnorm, out, partials);
  hipLaunchKernelGGL(norm_kernel, dim3(256), dim3(256), 0, stream, partials, gnw, gnb, out);
}

// Round 4
// 341.151 us; speedup vs baseline: 1.2313x; 1.2313x over previous
//
#include <hip/hip_runtime.h>
#include <stdint.h>

// Problem constants: B=32, H=8, N=257, D=64, DIM=512
#define WB_OFF   4210688ull
#define WA_OFF   21119232ull

typedef short short8 __attribute__((ext_vector_type(8)));
typedef float floatx4 __attribute__((ext_vector_type(4)));
typedef __attribute__((address_space(1))) const unsigned int gu32;
typedef __attribute__((address_space(3))) unsigned int lu32;

__device__ __forceinline__ unsigned short f2bf(float f){
  union { float f; uint32_t u; } v; v.f = f;
  uint32_t u = v.u;
  uint32_t r = (u + 0x7FFFu + ((u >> 16) & 1u)) >> 16;  // RNE
  return (unsigned short)r;
}

// ---- JAX Threefry-2x32 ----
__device__ __forceinline__ void threefry(uint32_t k0, uint32_t k1, uint32_t c0, uint32_t c1,
                                         uint32_t& o0, uint32_t& o1){
  const uint32_t ks2 = k0 ^ k1 ^ 0x1BD11BDAu;
  uint32_t x0 = c0 + k0, x1 = c1 + k1;
#define TF_R4(a,b,c,d) \
  x0+=x1; x1=(x1<<(a))|(x1>>(32-(a))); x1^=x0; \
  x0+=x1; x1=(x1<<(b))|(x1>>(32-(b))); x1^=x0; \
  x0+=x1; x1=(x1<<(c))|(x1>>(32-(c))); x1^=x0; \
  x0+=x1; x1=(x1<<(d))|(x1>>(32-(d))); x1^=x0;
  TF_R4(13,15,26,6)  x0+=k1;  x1+=ks2+1u;
  TF_R4(17,29,16,24) x0+=ks2; x1+=k0+2u;
  TF_R4(13,15,26,6)  x0+=k0;  x1+=k1+3u;
  TF_R4(17,29,16,24) x0+=k1;  x1+=ks2+4u;
  TF_R4(13,15,26,6)  x0+=ks2; x1+=k0+5u;
#undef TF_R4
  o0 = x0; o1 = x1;
}

// ---- Kernel A: noise + per-batch mask normalization (partitionable threefry) ----
__global__ __launch_bounds__(256) void prep_kernel(const int* __restrict__ msk,
                                                   float* __restrict__ mnorm){
  const int b = blockIdx.x, p = threadIdx.x;
  const int i = b*256 + p;
  uint32_t A0, A1, B0, B1;
  threefry(0u, 42u, 0u, 0u, A0, A1);   // k1
  threefry(0u, 42u, 0u, 1u, B0, B1);   // k2
  uint32_t h0, h1, l0, l1;
  threefry(A0, A1, 0u, (uint32_t)i, h0, h1);
  threefry(B0, B1, 0u, (uint32_t)i, l0, l1);
  uint32_t hb = h0 ^ h1, lb = l0 ^ l1;
  uint32_t off = ((hb % 127u) * 16u + (lb % 127u)) % 127u;
  int mv = msk[i];
  float m = (mv == 0) ? (float)(1u + off) : (float)mv;
  __shared__ float sm[256];
  sm[p] = m; __syncthreads();
  for (int s = 128; s > 0; s >>= 1){
    if (p < s) sm[p] = fmaxf(sm[p], sm[p+s]);
    __syncthreads();
  }
  mnorm[i] = m / sm[0];
}

// ---- Kernel A2: fp32 -> bf16 convert for x and w ----
// x: 4210688 floats = 1052672 float4 ; w: 786432 floats = 196608 float4
__global__ __launch_bounds__(256) void cvt_kernel(const float* __restrict__ x,
                                                  const float* __restrict__ w,
                                                  unsigned short* __restrict__ xb,
                                                  unsigned short* __restrict__ wb){
  int i = blockIdx.x*256 + threadIdx.x;
  if (i < 1052672){
    float4 v = ((const float4*)x)[i];
    ushort4 o; o.x=f2bf(v.x); o.y=f2bf(v.y); o.z=f2bf(v.z); o.w=f2bf(v.w);
    ((ushort4*)xb)[i] = o;
  } else if (i < 1249280){
    int j = i - 1052672;
    float4 v = ((const float4*)w)[j];
    ushort4 o; o.x=f2bf(v.x); o.y=f2bf(v.y); o.z=f2bf(v.z); o.w=f2bf(v.w);
    ((ushort4*)wb)[j] = o;
  }
}

// ---- Kernel B: QKV GEMM  qkv[8224,1536] = xb[8224,512] @ wb[1536,512]^T (bf16 MFMA)
// m97-style: 128x128 tile, BK=32, global_load_lds width 16. grid(12, 65), block 256.
__global__ __launch_bounds__(256) void qkv_gemm(const unsigned short* __restrict__ xb,
                                                const unsigned short* __restrict__ wb,
                                                unsigned short* __restrict__ qkv){
  __shared__ unsigned short al[128*32];
  __shared__ unsigned short bl[128*32];
  const int bn = blockIdx.x, bm = blockIdx.y;
  const int tid = threadIdx.x;
  const int wave = tid >> 6, lane = tid & 63;
  const int l16 = lane & 15, lq = lane >> 4;
  const int wm = (wave & 1) * 64, wn = (wave >> 1) * 64;
  const int row0 = tid >> 2, c8 = (tid & 3) * 8;
  floatx4 acc[4][4] = {};
  for (int kk = 0; kk < 512; kk += 32){
    #pragma unroll
    for (int r2 = 0; r2 < 2; r2++){
      int row = r2*64 + row0;
      int gm = bm*128 + row; if (gm > 8223) gm = 8223;
      __builtin_amdgcn_global_load_lds((gu32*)&xb[(size_t)gm*512 + kk + c8],
                                       (lu32*)&al[row*32 + c8], 16, 0, 0);
      int gn = bn*128 + row;   // 1536 = 12*128, always valid
      __builtin_amdgcn_global_load_lds((gu32*)&wb[(size_t)gn*512 + kk + c8],
                                       (lu32*)&bl[row*32 + c8], 16, 0, 0);
    }
    __syncthreads();
    short8 af[4], bf4[4];
    #pragma unroll
    for (int mi = 0; mi < 4; mi++) af[mi]  = *(const short8*)&al[(wm + mi*16 + l16)*32 + lq*8];
    #pragma unroll
    for (int ni = 0; ni < 4; ni++) bf4[ni] = *(const short8*)&bl[(wn + ni*16 + l16)*32 + lq*8];
    #pragma unroll
    for (int mi = 0; mi < 4; mi++)
      #pragma unroll
      for (int ni = 0; ni < 4; ni++)
        acc[mi][ni] = __builtin_amdgcn_mfma_f32_16x16x32_bf16(af[mi], bf4[ni], acc[mi][ni], 0, 0, 0);
    __syncthreads();
  }
  #pragma unroll
  for (int mi = 0; mi < 4; mi++)
    #pragma unroll
    for (int ni = 0; ni < 4; ni++)
      #pragma unroll
      for (int r = 0; r < 4; r++){
        int gm = bm*128 + wm + mi*16 + lq*4 + r;
        if (gm < 8224){
          int gn = bn*128 + wn + ni*16 + l16;
          qkv[(size_t)gm*1536 + gn] = f2bf(acc[mi][ni][r]);
        }
      }
}

// ---- Kernel C: fused retention. grid(5, 256).
// LDS (dynamic 76832 B):
//   phase A: kl[272][68] @0 (36992), ql[64][68] @36992 (8704), pkl[64][68] @45696 (8704)
//   phase B: ftile f32[64*257] @0 (65792)
//   phase C: pl[64][296] @0 (37888), vT[64][296] @37888 (37888)
//   mn[256]f @75776, red[8]f @76800
__global__ __launch_bounds__(256) void retention_kernel(
    const unsigned short* __restrict__ qkv,
    const float* __restrict__ past_kv,
    const float* __restrict__ mnorm,
    float* __restrict__ out,
    float* __restrict__ partials){
  const int t  = blockIdx.x;
  const int bh = blockIdx.y;
  const int b = bh >> 3, h = bh & 7;
  const int tid = threadIdx.x;
  const int wave = tid >> 6, lane = tid & 63;
  const int l16 = lane & 15, lq = lane >> 4;
  const int rw = wave * 16;

  extern __shared__ unsigned char smem[];
  unsigned short* kl  = (unsigned short*)smem;             // [272][68]
  unsigned short* ql  = (unsigned short*)(smem + 36992);   // [64][68]
  unsigned short* pkl = (unsigned short*)(smem + 45696);   // [64][68]
  float* ftile        = (float*)smem;                      // [64*257]
  unsigned short* pl  = (unsigned short*)smem;             // [64][296]
  unsigned short* vT  = (unsigned short*)(smem + 37888);   // [64][296]
  float* mn  = (float*)(smem + 75776);
  float* red = (float*)(smem + 76800);

  // ---- phase 0: stage k (+15 zero pad rows), q tile, 0.125*past_kv^T, mn
  {
    uint32_t* z = (uint32_t*)(kl + 257*68);
    for (int i = tid; i < 510; i += 256) z[i] = 0;
  }
  for (int c = tid; c < 257*16; c += 256){
    int row = c >> 4, c4 = (c & 15) * 4;
    ushort4 v = *(const ushort4*)&qkv[(size_t)(b*257 + row)*1536 + 512 + h*64 + c4];
    *(ushort4*)&kl[row*68 + c4] = v;
  }
  for (int c = tid; c < 64*16; c += 256){
    int row = c >> 4, c4 = (c & 15) * 4;
    int gi0 = t*64 + row; if (gi0 > 256) gi0 = 256;
    ushort4 v = *(const ushort4*)&qkv[(size_t)(b*257 + gi0)*1536 + h*64 + c4];
    *(ushort4*)&ql[row*68 + c4] = v;
  }
  for (int c = tid; c < 64*16; c += 256){
    int d = c >> 4, e4 = (c & 15) * 4;
    float4 v = *(const float4*)&past_kv[(size_t)bh*4096 + d*64 + e4];
    pkl[(e4+0)*68 + d] = f2bf(0.125f * v.x);
    pkl[(e4+1)*68 + d] = f2bf(0.125f * v.y);
    pkl[(e4+2)*68 + d] = f2bf(0.125f * v.z);
    pkl[(e4+3)*68 + d] = f2bf(0.125f * v.w);
  }
  mn[tid] = mnorm[b*256 + tid];
  __syncthreads();

  // ---- cross-retention: acc2 = q @ (0.125*past_kv)
  floatx4 acc2[4] = {};
  #pragma unroll
  for (int ks = 0; ks < 2; ks++){
    short8 a = *(const short8*)&ql[(rw + l16)*68 + ks*32 + lq*8];
    #pragma unroll
    for (int ni = 0; ni < 4; ni++){
      short8 bb = *(const short8*)&pkl[(ni*16 + l16)*68 + ks*32 + lq*8];
      acc2[ni] = __builtin_amdgcn_mfma_f32_16x16x32_bf16(a, bb, acc2[ni], 0, 0, 0);
    }
  }

  // ---- S = 0.125 * q @ k^T
  floatx4 acc[17] = {};
  #pragma unroll
  for (int ks = 0; ks < 2; ks++){
    short8 a = *(const short8*)&ql[(rw + l16)*68 + ks*32 + lq*8];
    #pragma unroll
    for (int c = 0; c < 17; c++){
      short8 bb = *(const short8*)&kl[(c*16 + l16)*68 + ks*32 + lq*8];
      acc[c] = __builtin_amdgcn_mfma_f32_16x16x32_bf16(a, bb, acc[c], 0, 0, 0);
    }
  }
  #pragma unroll
  for (int c = 0; c < 17; c++) acc[c] *= 0.125f;

  __syncthreads();   // k,q,pk dead -> ftile live

  int gi[4]; bool rowok[4];
  #pragma unroll
  for (int r = 0; r < 4; r++){ gi[r] = t*64 + rw + lq*4 + r; rowok[r] = (gi[r] < 257); }
  const int rloc = rw + lq*4;   // local row base for this thread's C-frags

  // ---- softmax1: mx, sum, then e*inv -> ftile
  float mx[4], sum_[4], inv_[4];
  #pragma unroll
  for (int r = 0; r < 4; r++) mx[r] = -3.0e38f;
  #pragma unroll
  for (int c = 0; c < 17; c++){
    bool jok = (c < 16) || (l16 == 0);
    if (jok){
      #pragma unroll
      for (int r = 0; r < 4; r++) mx[r] = fmaxf(mx[r], acc[c][r]);
    }
  }
  #pragma unroll
  for (int m = 1; m < 16; m <<= 1)
    #pragma unroll
    for (int r = 0; r < 4; r++) mx[r] = fmaxf(mx[r], __shfl_xor(mx[r], m, 64));
  #pragma unroll
  for (int r = 0; r < 4; r++) sum_[r] = 0.f;
  #pragma unroll
  for (int c = 0; c < 17; c++){
    bool jok = (c < 16) || (l16 == 0);
    if (jok){
      #pragma unroll
      for (int r = 0; r < 4; r++) sum_[r] += __expf((acc[c][r] - mx[r]) * 0.125f);
    }
  }
  #pragma unroll
  for (int m = 1; m < 16; m <<= 1)
    #pragma unroll
    for (int r = 0; r < 4; r++) sum_[r] += __shfl_xor(sum_[r], m, 64);
  #pragma unroll
  for (int r = 0; r < 4; r++) inv_[r] = 1.0f / sum_[r];
  #pragma unroll
  for (int c = 0; c < 17; c++){
    int j = c*16 + l16;
    if (j < 257){
      #pragma unroll
      for (int r = 0; r < 4; r++)
        ftile[(rloc + r)*257 + j] = __expf((acc[c][r] - mx[r]) * 0.125f) * inv_[r];
    }
  }
  __syncthreads();

  // ---- stream weights_before (contiguous 64x257 region per tile)
  const int nval = (t == 4) ? 257 : 16448;
  {
    const size_t gbase = WB_OFF + (size_t)bh*66049 + (size_t)t*16448;
    const int a0 = (int)(gbase & 3), o0 = (4 - a0) & 3;
    const float* fs = (const float*)smem;
    if (tid < o0 && tid < nval) out[gbase + tid] = fs[tid];
    for (int k2 = 0; k2 < 17; k2++){
      int lin = o0 + (tid + k2*256)*4;
      if (lin + 3 < nval){
        float4 v; v.x = fs[lin]; v.y = fs[lin+1]; v.z = fs[lin+2]; v.w = fs[lin+3];
        *(float4*)&out[gbase + lin] = v;
      } else if (lin < nval){
        #pragma unroll
        for (int e = 0; e < 4; e++) if (lin + e < nval) out[gbase + lin + e] = fs[lin + e];
      }
    }
  }

  // ---- mask in registers (no barrier needed: regs + mn only)
  #pragma unroll
  for (int c = 0; c < 17; c++){
    int j = c*16 + l16;
    #pragma unroll
    for (int r = 0; r < 4; r++){
      int ii = gi[r] > 256 ? 256 : gi[r];
      float mv;
      if (j > ii)       mv = 0.f;
      else if (j == ii) mv = 1.f;
      else if (j == 0)  mv = __expf(-5.f * (float)ii * (1.f/256.f));
      else              mv = mn[ii-1] * mn[j-1];
      acc[c][r] *= mv;
    }
  }

  // ---- softmax2 statistics
  #pragma unroll
  for (int r = 0; r < 4; r++) mx[r] = -3.0e38f;
  #pragma unroll
  for (int c = 0; c < 17; c++){
    bool jok = (c < 16) || (l16 == 0);
    if (jok){
      #pragma unroll
      for (int r = 0; r < 4; r++) mx[r] = fmaxf(mx[r], acc[c][r]);
    }
  }
  #pragma unroll
  for (int m = 1; m < 16; m <<= 1)
    #pragma unroll
    for (int r = 0; r < 4; r++) mx[r] = fmaxf(mx[r], __shfl_xor(mx[r], m, 64));
  #pragma unroll
  for (int r = 0; r < 4; r++) sum_[r] = 0.f;
  #pragma unroll
  for (int c = 0; c < 17; c++){
    bool jok = (c < 16) || (l16 == 0);
    if (jok){
      #pragma unroll
      for (int r = 0; r < 4; r++) sum_[r] += __expf((acc[c][r] - mx[r]) * 0.125f);
    }
  }
  #pragma unroll
  for (int m = 1; m < 16; m <<= 1)
    #pragma unroll
    for (int r = 0; r < 4; r++) sum_[r] += __shfl_xor(sum_[r], m, 64);
  #pragma unroll
  for (int r = 0; r < 4; r++) inv_[r] = 1.0f / sum_[r];

  __syncthreads();   // all waves done reading ftile (WB stream)

  // ---- e2*inv2 -> ftile
  #pragma unroll
  for (int c = 0; c < 17; c++){
    int j = c*16 + l16;
    if (j < 257){
      #pragma unroll
      for (int r = 0; r < 4; r++)
        ftile[(rloc + r)*257 + j] = __expf((acc[c][r] - mx[r]) * 0.125f) * inv_[r];
    }
  }
  __syncthreads();

  // ---- stream weights_after
  {
    const size_t gbase = WA_OFF + (size_t)bh*66049 + (size_t)t*16448;
    const int a0 = (int)(gbase & 3), o0 = (4 - a0) & 3;
    const float* fs = (const float*)smem;
    if (tid < o0 && tid < nval) out[gbase + tid] = fs[tid];
    for (int k2 = 0; k2 < 17; k2++){
      int lin = o0 + (tid + k2*256)*4;
      if (lin + 3 < nval){
        float4 v; v.x = fs[lin]; v.y = fs[lin+1]; v.z = fs[lin+2]; v.w = fs[lin+3];
        *(float4*)&out[gbase + lin] = v;
      } else if (lin < nval){
        #pragma unroll
        for (int e = 0; e < 4; e++) if (lin + e < nval) out[gbase + lin + e] = fs[lin + e];
      }
    }
  }
  __syncthreads();   // ftile dead -> pl/vT live

  // ---- build P (masked, unnormalized, bf16, [64][296]) and vT ([e][j] bf16 [64][296])
  {  // zero pad cols 256..295 of both pl and vT (rows x 40 ushorts = 1280 uints each)
    for (int i = tid; i < 1280; i += 256){
      int row = i / 20, cc = (i % 20)*2 + 256;
      *(uint32_t*)&pl[row*296 + cc] = 0;
      *(uint32_t*)&vT[row*296 + cc] = 0;
    }
  }
  #pragma unroll
  for (int c = 0; c < 17; c++){
    int j = c*16 + l16;
    if (j < 257){
      #pragma unroll
      for (int r = 0; r < 4; r++) pl[(rloc + r)*296 + j] = f2bf(acc[c][r]);
    }
  }
  for (int c = tid; c < 257*16; c += 256){
    int row = c >> 4, c4 = (c & 15) * 4;
    ushort4 v = *(const ushort4*)&qkv[(size_t)(b*257 + row)*1536 + 1024 + h*64 + c4];
    vT[(c4+0)*296 + row] = v.x;
    vT[(c4+1)*296 + row] = v.y;
    vT[(c4+2)*296 + row] = v.z;
    vT[(c4+3)*296 + row] = v.w;
  }
  __syncthreads();

  // ---- inner = P @ V (tril-aware K extent), accumulate onto cross
  const int nks = (t == 4) ? 9 : (2*t + 2);
  for (int ks = 0; ks < nks; ks++){
    short8 a = *(const short8*)&pl[(rw + l16)*296 + ks*32 + lq*8];
    #pragma unroll
    for (int ni = 0; ni < 4; ni++){
      short8 bb = *(const short8*)&vT[(ni*16 + l16)*296 + ks*32 + lq*8];
      acc2[ni] = __builtin_amdgcn_mfma_f32_16x16x32_bf16(a, bb, acc2[ni], 0, 0, 0);
    }
  }

  // ---- r = inner + cross: store pre-norm + GroupNorm partials
  float ls = 0.f, lss = 0.f;
  #pragma unroll
  for (int ni = 0; ni < 4; ni++)
    #pragma unroll
    for (int r = 0; r < 4; r++)
      if (rowok[r]){
        float v = acc2[ni][r];
        ls += v; lss += v*v;
        out[(size_t)(b*257 + gi[r])*512 + h*64 + ni*16 + l16] = v;
      }
  #pragma unroll
  for (int m = 1; m < 64; m <<= 1){ ls += __shfl_xor(ls, m, 64); lss += __shfl_xor(lss, m, 64); }
  if (lane == 0){ red[wave*2] = ls; red[wave*2 + 1] = lss; }
  __syncthreads();
  if (tid == 0){
    partials[((size_t)bh*5 + t)*2 + 0] = red[0] + red[2] + red[4] + red[6];
    partials[((size_t)bh*5 + t)*2 + 1] = red[1] + red[3] + red[5] + red[7];
  }
}

// ---- Kernel D: GroupNorm finalize in place. grid(256) = (b,h) ----
__global__ __launch_bounds__(256) void norm_kernel(const float* __restrict__ partials,
                                                   const float* __restrict__ gnw,
                                                   const float* __restrict__ gnb,
                                                   float* __restrict__ out){
  const int bh = blockIdx.x, b = bh >> 3, h = bh & 7;
  float s = 0.f, s2 = 0.f;
  #pragma unroll
  for (int tt = 0; tt < 5; tt++){
    s  += partials[(bh*5 + tt)*2 + 0];
    s2 += partials[(bh*5 + tt)*2 + 1];
  }
  const float cnt = 257.f * 64.f;
  float mean = s / cnt;
  float var  = s2 / cnt - mean * mean;
  float isd  = rsqrtf(var + 1e-5f);
  float wsc  = gnw[h] * isd;
  float bia  = gnb[h] - mean * wsc;
  for (int idx = threadIdx.x; idx < 257*16; idx += 256){
    int n = idx >> 4, e4 = (idx & 15) * 4;
    size_t off = (size_t)(b*257 + n)*512 + h*64 + e4;
    float4 v = *(float4*)&out[off];
    v.x = v.x * wsc + bia; v.y = v.y * wsc + bia;
    v.z = v.z * wsc + bia; v.w = v.w * wsc + bia;
    *(float4*)&out[off] = v;
  }
}

extern "C" void kernel_launch(void* const* d_in, const int* in_sizes, int n_in,
                              void* d_out, int out_size, void* d_ws, size_t ws_size,
                              hipStream_t stream){
  (void)in_sizes; (void)n_in; (void)out_size; (void)ws_size;
  const float* x   = (const float*)d_in[0];
  const int*   msk = (const int*)d_in[1];
  const float* w   = (const float*)d_in[2];
  const float* pkv = (const float*)d_in[3];
  const float* gnw = (const float*)d_in[4];
  const float* gnb = (const float*)d_in[5];
  float* out = (float*)d_out;

  unsigned short* qkv = (unsigned short*)d_ws;                       // 25264128 B
  unsigned short* xb  = (unsigned short*)((char*)d_ws + 25264128);   // 8421376 B
  unsigned short* wb  = (unsigned short*)((char*)d_ws + 33685504);   // 1572864 B
  float* mnorm    = (float*)((char*)d_ws + 35258368);                // 32768 B
  float* partials = (float*)((char*)d_ws + 35291136);                // 10240 B

  hipLaunchKernelGGL(prep_kernel, dim3(32), dim3(256), 0, stream, msk, mnorm);
  hipLaunchKernelGGL(cvt_kernel, dim3(4880), dim3(256), 0, stream, x, w, xb, wb);
  hipLaunchKernelGGL(qkv_gemm, dim3(12, 65), dim3(256), 0, stream, xb, wb, qkv);
  hipLaunchKernelGGL(retention_kernel, dim3(5, 256), dim3(256), 76832, stream,
                     qkv, pkv, mnorm, out, partials);
  hipLaunchKernelGGL(norm_kernel, dim3(256), dim3(256), 0, stream, partials, gnw, gnb, out);
}

// Round 5
// 320.613 us; speedup vs baseline: 1.3102x; 1.0641x over previous
//
#include <hip/hip_runtime.h>
#include <stdint.h>

// Problem constants: B=32, H=8, N=257, D=64, DIM=512
#define WB_OFF   4210688ull
#define WA_OFF   21119232ull

typedef short short8 __attribute__((ext_vector_type(8)));
typedef float floatx4 __attribute__((ext_vector_type(4)));
typedef __attribute__((address_space(1))) const unsigned int gu32;
typedef __attribute__((address_space(3))) unsigned int lu32;

__device__ __forceinline__ unsigned short f2bf(float f){
  union { float f; uint32_t u; } v; v.f = f;
  uint32_t u = v.u;
  uint32_t r = (u + 0x7FFFu + ((u >> 16) & 1u)) >> 16;  // RNE
  return (unsigned short)r;
}

// ---- JAX Threefry-2x32 ----
__device__ __forceinline__ void threefry(uint32_t k0, uint32_t k1, uint32_t c0, uint32_t c1,
                                         uint32_t& o0, uint32_t& o1){
  const uint32_t ks2 = k0 ^ k1 ^ 0x1BD11BDAu;
  uint32_t x0 = c0 + k0, x1 = c1 + k1;
#define TF_R4(a,b,c,d) \
  x0+=x1; x1=(x1<<(a))|(x1>>(32-(a))); x1^=x0; \
  x0+=x1; x1=(x1<<(b))|(x1>>(32-(b))); x1^=x0; \
  x0+=x1; x1=(x1<<(c))|(x1>>(32-(c))); x1^=x0; \
  x0+=x1; x1=(x1<<(d))|(x1>>(32-(d))); x1^=x0;
  TF_R4(13,15,26,6)  x0+=k1;  x1+=ks2+1u;
  TF_R4(17,29,16,24) x0+=ks2; x1+=k0+2u;
  TF_R4(13,15,26,6)  x0+=k0;  x1+=k1+3u;
  TF_R4(17,29,16,24) x0+=k1;  x1+=ks2+4u;
  TF_R4(13,15,26,6)  x0+=ks2; x1+=k0+5u;
#undef TF_R4
  o0 = x0; o1 = x1;
}

// ---- Kernel A: noise + per-batch mask normalization (partitionable threefry) ----
__global__ __launch_bounds__(256) void prep_kernel(const int* __restrict__ msk,
                                                   float* __restrict__ mnorm){
  const int b = blockIdx.x, p = threadIdx.x;
  const int i = b*256 + p;
  uint32_t A0, A1, B0, B1;
  threefry(0u, 42u, 0u, 0u, A0, A1);   // k1
  threefry(0u, 42u, 0u, 1u, B0, B1);   // k2
  uint32_t h0, h1, l0, l1;
  threefry(A0, A1, 0u, (uint32_t)i, h0, h1);
  threefry(B0, B1, 0u, (uint32_t)i, l0, l1);
  uint32_t hb = h0 ^ h1, lb = l0 ^ l1;
  uint32_t off = ((hb % 127u) * 16u + (lb % 127u)) % 127u;
  int mv = msk[i];
  float m = (mv == 0) ? (float)(1u + off) : (float)mv;
  __shared__ float sm[256];
  sm[p] = m; __syncthreads();
  for (int s = 128; s > 0; s >>= 1){
    if (p < s) sm[p] = fmaxf(sm[p], sm[p+s]);
    __syncthreads();
  }
  mnorm[i] = m / sm[0];
}

// ---- Kernel A2: fp32 -> bf16 convert for x and w ----
__global__ __launch_bounds__(256) void cvt_kernel(const float* __restrict__ x,
                                                  const float* __restrict__ w,
                                                  unsigned short* __restrict__ xb,
                                                  unsigned short* __restrict__ wb){
  int i = blockIdx.x*256 + threadIdx.x;
  if (i < 1052672){
    float4 v = ((const float4*)x)[i];
    ushort4 o; o.x=f2bf(v.x); o.y=f2bf(v.y); o.z=f2bf(v.z); o.w=f2bf(v.w);
    ((ushort4*)xb)[i] = o;
  } else if (i < 1249280){
    int j = i - 1052672;
    float4 v = ((const float4*)w)[j];
    ushort4 o; o.x=f2bf(v.x); o.y=f2bf(v.y); o.z=f2bf(v.z); o.w=f2bf(v.w);
    ((ushort4*)wb)[j] = o;
  }
}

// ---- Kernel B: QKV GEMM  qkv[8224,1536] = xb[8224,512] @ wb[1536,512]^T
// 128x128 tile, BK=64 (8 iters), global_load_lds + XOR col swizzle (conflict-free
// ds_read with unpadded lane-linear LDS). Coalesced C store via LDS. grid(12,65).
__global__ __launch_bounds__(256) void qkv_gemm(const unsigned short* __restrict__ xb,
                                                const unsigned short* __restrict__ wb,
                                                unsigned short* __restrict__ qkv){
  __shared__ unsigned short sm2[128*64*2 + 128*8];  // al/bl 32768B; c_lds [128][136] 34816B
  unsigned short* al = sm2;              // [128][64] lane-linear, col chunks XOR-swizzled
  unsigned short* bl = sm2 + 128*64;
  unsigned short* c_lds = sm2;           // [128][136] (reuse after K-loop)
  const int bn = blockIdx.x, bm = blockIdx.y;
  const int tid = threadIdx.x;
  const int wave = tid >> 6, lane = tid & 63;
  const int l16 = lane & 15, lq = lane >> 4;
  const int wm = (wave & 1) * 64, wn = (wave >> 1) * 64;
  const int row0 = tid >> 3;
  const int ccg = ((tid & 7) ^ (row0 & 7)) * 8;   // swizzled global col chunk
  const int sx = (l16 & 7);                        // compute-side swizzle key
  floatx4 acc[4][4] = {};
  for (int kk = 0; kk < 512; kk += 64){
    #pragma unroll
    for (int p = 0; p < 4; p++){
      int row = p*32 + row0;
      int gm = bm*128 + row; if (gm > 8223) gm = 8223;
      __builtin_amdgcn_global_load_lds((gu32*)&xb[(size_t)gm*512 + kk + ccg],
                                       (lu32*)&al[row*64 + (tid & 7)*8], 16, 0, 0);
      int gn = bn*128 + row;
      __builtin_amdgcn_global_load_lds((gu32*)&wb[(size_t)gn*512 + kk + ccg],
                                       (lu32*)&bl[row*64 + (tid & 7)*8], 16, 0, 0);
    }
    __syncthreads();
    #pragma unroll
    for (int ks = 0; ks < 2; ks++){
      short8 af[4], bf4[4];
      #pragma unroll
      for (int mi = 0; mi < 4; mi++){
        int ch = (ks*4 + lq) ^ sx;
        af[mi] = *(const short8*)&al[(wm + mi*16 + l16)*64 + ch*8];
      }
      #pragma unroll
      for (int ni = 0; ni < 4; ni++){
        int ch = (ks*4 + lq) ^ sx;
        bf4[ni] = *(const short8*)&bl[(wn + ni*16 + l16)*64 + ch*8];
      }
      #pragma unroll
      for (int mi = 0; mi < 4; mi++)
        #pragma unroll
        for (int ni = 0; ni < 4; ni++)
          acc[mi][ni] = __builtin_amdgcn_mfma_f32_16x16x32_bf16(af[mi], bf4[ni], acc[mi][ni], 0, 0, 0);
    }
    __syncthreads();
  }
  // epilogue: C tile -> LDS [128][136] -> coalesced 16B stores
  #pragma unroll
  for (int mi = 0; mi < 4; mi++)
    #pragma unroll
    for (int ni = 0; ni < 4; ni++)
      #pragma unroll
      for (int r = 0; r < 4; r++)
        c_lds[(wm + mi*16 + lq*4 + r)*136 + wn + ni*16 + l16] = f2bf(acc[mi][ni][r]);
  __syncthreads();
  for (int i = tid; i < 128*16; i += 256){
    int row = i >> 4, cc = (i & 15)*8;
    int gm = bm*128 + row;
    if (gm < 8224){
      ushort4 v0 = *(const ushort4*)&c_lds[row*136 + cc];
      ushort4 v1 = *(const ushort4*)&c_lds[row*136 + cc + 4];
      *(ushort4*)&qkv[(size_t)gm*1536 + bn*128 + cc] = v0;
      *(ushort4*)&qkv[(size_t)gm*1536 + bn*128 + cc + 4] = v1;
    }
  }
}

// ---- Kernel C: fused retention. grid(5, 256): x=row tile (64 rows), y=(b*8+h).
// LDS (dynamic 49440 B), 3 blocks/CU:
//   X [0,39168):   kl[272][72]  ->  bufw (per-wave [8][257] f32, wave*8224)  ->  vT[64][296]
//   Y [39168,48384): pkl[64][72] ->  plw (per-wave [16][40], 39168+wave*1280)
//   mn [48384,49408), red [49408,49440)
__global__ __launch_bounds__(256, 3) void retention_kernel(
    const unsigned short* __restrict__ qkv,
    const float* __restrict__ past_kv,
    const float* __restrict__ mnorm,
    float* __restrict__ out,
    float* __restrict__ partials){
  const int t  = blockIdx.x;
  const int bh = blockIdx.y;
  const int b = bh >> 3, h = bh & 7;
  const int tid = threadIdx.x;
  const int wave = tid >> 6, lane = tid & 63;
  const int l16 = lane & 15, lq = lane >> 4;
  const int rw = wave * 16;

  extern __shared__ unsigned char smem[];
  unsigned short* kl  = (unsigned short*)smem;                    // [272][72]
  unsigned short* vT  = (unsigned short*)smem;                    // [64][296]
  float* bufw         = (float*)(smem + wave*8224);               // [8][257]
  unsigned short* pkl = (unsigned short*)(smem + 39168);          // [64][72]
  unsigned short* plw = (unsigned short*)(smem + 39168 + wave*1280); // [16][40]
  float* mn  = (float*)(smem + 48384);
  float* red = (float*)(smem + 49408);

  // ---- phase A: stage k (+15 zero pad rows), 0.125*past_kv^T, mn; q -> regs
  {
    uint32_t* z = (uint32_t*)(kl + 257*72);
    for (int i = tid; i < 540; i += 256) z[i] = 0;
  }
  for (int c = tid; c < 257*16; c += 256){
    int row = c >> 4, c4 = (c & 15) * 4;
    ushort4 v = *(const ushort4*)&qkv[(size_t)(b*257 + row)*1536 + 512 + h*64 + c4];
    *(ushort4*)&kl[row*72 + c4] = v;
  }
  for (int c = tid; c < 64*16; c += 256){
    int d = c >> 4, e4 = (c & 15) * 4;
    float4 v = *(const float4*)&past_kv[(size_t)bh*4096 + d*64 + e4];
    pkl[(e4+0)*72 + d] = f2bf(0.125f * v.x);
    pkl[(e4+1)*72 + d] = f2bf(0.125f * v.y);
    pkl[(e4+2)*72 + d] = f2bf(0.125f * v.z);
    pkl[(e4+3)*72 + d] = f2bf(0.125f * v.w);
  }
  mn[tid] = mnorm[b*256 + tid];
  int giA = t*64 + rw + l16; if (giA > 256) giA = 256;
  short8 aq[2];
  aq[0] = *(const short8*)&qkv[(size_t)(b*257 + giA)*1536 + h*64 + lq*8];
  aq[1] = *(const short8*)&qkv[(size_t)(b*257 + giA)*1536 + h*64 + 32 + lq*8];
  __syncthreads();                                   // (1)

  // ---- cross-retention: acc2 = q @ (0.125*past_kv)
  floatx4 acc2[4] = {};
  #pragma unroll
  for (int ks = 0; ks < 2; ks++)
    #pragma unroll
    for (int ni = 0; ni < 4; ni++){
      short8 bb = *(const short8*)&pkl[(ni*16 + l16)*72 + ks*32 + lq*8];
      acc2[ni] = __builtin_amdgcn_mfma_f32_16x16x32_bf16(aq[ks], bb, acc2[ni], 0, 0, 0);
    }

  // ---- S = 0.125 * q @ k^T
  floatx4 acc[17] = {};
  #pragma unroll
  for (int ks = 0; ks < 2; ks++)
    #pragma unroll
    for (int c = 0; c < 17; c++){
      short8 bb = *(const short8*)&kl[(c*16 + l16)*72 + ks*32 + lq*8];
      acc[c] = __builtin_amdgcn_mfma_f32_16x16x32_bf16(aq[ks], bb, acc[c], 0, 0, 0);
    }
  #pragma unroll
  for (int c = 0; c < 17; c++) acc[c] *= 0.125f;

  __syncthreads();                                   // (2) kl/pkl dead -> bufw live

  int gi[4]; bool rowok[4];
  #pragma unroll
  for (int r = 0; r < 4; r++){ gi[r] = t*64 + rw + lq*4 + r; rowok[r] = (gi[r] < 257); }

  float mx[4], sum_[4], inv_[4];

  // ================= softmax1 -> weights_before (wave-local stream) =================
  #pragma unroll
  for (int r = 0; r < 4; r++) mx[r] = -3.0e38f;
  #pragma unroll
  for (int c = 0; c < 17; c++){
    bool jok = (c < 16) || (l16 == 0);
    if (jok){
      #pragma unroll
      for (int r = 0; r < 4; r++) mx[r] = fmaxf(mx[r], acc[c][r]);
    }
  }
  #pragma unroll
  for (int m = 1; m < 16; m <<= 1)
    #pragma unroll
    for (int r = 0; r < 4; r++) mx[r] = fmaxf(mx[r], __shfl_xor(mx[r], m, 64));
  #pragma unroll
  for (int r = 0; r < 4; r++) sum_[r] = 0.f;
  #pragma unroll
  for (int c = 0; c < 17; c++){
    bool jok = (c < 16) || (l16 == 0);
    if (jok){
      #pragma unroll
      for (int r = 0; r < 4; r++) sum_[r] += __expf((acc[c][r] - mx[r]) * 0.125f);
    }
  }
  #pragma unroll
  for (int m = 1; m < 16; m <<= 1)
    #pragma unroll
    for (int r = 0; r < 4; r++) sum_[r] += __shfl_xor(sum_[r], m, 64);
  #pragma unroll
  for (int r = 0; r < 4; r++) inv_[r] = 1.0f / sum_[r];

  #pragma unroll
  for (int hh = 0; hh < 2; hh++){
    if ((lq >> 1) == hh){
      int lr0 = lq*4 - hh*8;
      #pragma unroll
      for (int c = 0; c < 17; c++){
        int j = c*16 + l16;
        if (j < 257){
          #pragma unroll
          for (int r = 0; r < 4; r++)
            bufw[(lr0 + r)*257 + j] = __expf((acc[c][r] - mx[r]) * 0.125f) * inv_[r];
        }
      }
    }
    int row0 = t*64 + rw + hh*8;
    int nrow = 257 - row0; if (nrow < 0) nrow = 0; if (nrow > 8) nrow = 8;
    int n = nrow * 257;
    if (n > 0){
      size_t gb = WB_OFF + (size_t)bh*66049 + (size_t)row0*257;
      int o0 = (int)((4 - (gb & 3)) & 3);
      if (lane < o0 && lane < n) out[gb + lane] = bufw[lane];
      for (int base = o0 + lane*4; base < n; base += 256){
        if (base + 3 < n){
          float4 v; v.x = bufw[base]; v.y = bufw[base+1]; v.z = bufw[base+2]; v.w = bufw[base+3];
          *(float4*)&out[gb + base] = v;
        } else {
          #pragma unroll
          for (int e = 0; e < 4; e++) if (base + e < n) out[gb + base + e] = bufw[base + e];
        }
      }
    }
  }

  // ---- apply mask in registers
  #pragma unroll
  for (int c = 0; c < 17; c++){
    int j = c*16 + l16;
    #pragma unroll
    for (int r = 0; r < 4; r++){
      int ii = gi[r] > 256 ? 256 : gi[r];
      float mv;
      if (j > ii)       mv = 0.f;
      else if (j == ii) mv = 1.f;
      else if (j == 0)  mv = __expf(-5.f * (float)ii * (1.f/256.f));
      else              mv = mn[ii-1] * mn[j-1];
      acc[c][r] *= mv;
    }
  }

  // ================= softmax2 -> weights_after (wave-local stream) =================
  #pragma unroll
  for (int r = 0; r < 4; r++) mx[r] = -3.0e38f;
  #pragma unroll
  for (int c = 0; c < 17; c++){
    bool jok = (c < 16) || (l16 == 0);
    if (jok){
      #pragma unroll
      for (int r = 0; r < 4; r++) mx[r] = fmaxf(mx[r], acc[c][r]);
    }
  }
  #pragma unroll
  for (int m = 1; m < 16; m <<= 1)
    #pragma unroll
    for (int r = 0; r < 4; r++) mx[r] = fmaxf(mx[r], __shfl_xor(mx[r], m, 64));
  #pragma unroll
  for (int r = 0; r < 4; r++) sum_[r] = 0.f;
  #pragma unroll
  for (int c = 0; c < 17; c++){
    bool jok = (c < 16) || (l16 == 0);
    if (jok){
      #pragma unroll
      for (int r = 0; r < 4; r++) sum_[r] += __expf((acc[c][r] - mx[r]) * 0.125f);
    }
  }
  #pragma unroll
  for (int m = 1; m < 16; m <<= 1)
    #pragma unroll
    for (int r = 0; r < 4; r++) sum_[r] += __shfl_xor(sum_[r], m, 64);
  #pragma unroll
  for (int r = 0; r < 4; r++) inv_[r] = 1.0f / sum_[r];

  #pragma unroll
  for (int hh = 0; hh < 2; hh++){
    if ((lq >> 1) == hh){
      int lr0 = lq*4 - hh*8;
      #pragma unroll
      for (int c = 0; c < 17; c++){
        int j = c*16 + l16;
        if (j < 257){
          #pragma unroll
          for (int r = 0; r < 4; r++)
            bufw[(lr0 + r)*257 + j] = __expf((acc[c][r] - mx[r]) * 0.125f) * inv_[r];
        }
      }
    }
    int row0 = t*64 + rw + hh*8;
    int nrow = 257 - row0; if (nrow < 0) nrow = 0; if (nrow > 8) nrow = 8;
    int n = nrow * 257;
    if (n > 0){
      size_t gb = WA_OFF + (size_t)bh*66049 + (size_t)row0*257;
      int o0 = (int)((4 - (gb & 3)) & 3);
      if (lane < o0 && lane < n) out[gb + lane] = bufw[lane];
      for (int base = o0 + lane*4; base < n; base += 256){
        if (base + 3 < n){
          float4 v; v.x = bufw[base]; v.y = bufw[base+1]; v.z = bufw[base+2]; v.w = bufw[base+3];
          *(float4*)&out[gb + base] = v;
        } else {
          #pragma unroll
          for (int e = 0; e < 4; e++) if (base + e < n) out[gb + base + e] = bufw[base + e];
        }
      }
    }
  }
  __syncthreads();                                   // (3) bufw dead -> vT live

  // ---- stage vT[e][j] (zero pads j=257..295; col 256 staged by v loop)
  for (int i = tid; i < 64*19; i += 256){
    int row = i / 19, cc = (i % 19)*2 + 258;
    *(uint32_t*)&vT[row*296 + cc] = 0;
  }
  if (tid < 64) vT[tid*296 + 257] = 0;
  for (int c = tid; c < 257*16; c += 256){
    int row = c >> 4, c4 = (c & 15) * 4;
    ushort4 v = *(const ushort4*)&qkv[(size_t)(b*257 + row)*1536 + 1024 + h*64 + c4];
    vT[(c4+0)*296 + row] = v.x;
    vT[(c4+1)*296 + row] = v.y;
    vT[(c4+2)*296 + row] = v.z;
    vT[(c4+3)*296 + row] = v.w;
  }
  __syncthreads();                                   // (4) vT ready

  // ---- inner = P @ V via wave-local 16x32 P-chunks (no cross-wave barriers)
  const int nks = (t == 4) ? 9 : (2*t + 2);
  for (int ks = 0; ks < nks; ks++){
    #pragma unroll
    for (int cc = 0; cc < 2; cc++){
      int f = ks*2 + cc;
      #pragma unroll
      for (int r = 0; r < 4; r++){
        float val = (f < 17 && (f*16 + l16) < 257) ? acc[f][r] : 0.f;
        plw[(lq*4 + r)*40 + cc*16 + l16] = f2bf(val);
      }
    }
    short8 a = *(const short8*)&plw[l16*40 + lq*8];
    #pragma unroll
    for (int ni = 0; ni < 4; ni++){
      short8 bb = *(const short8*)&vT[(ni*16 + l16)*296 + ks*32 + lq*8];
      acc2[ni] = __builtin_amdgcn_mfma_f32_16x16x32_bf16(a, bb, acc2[ni], 0, 0, 0);
    }
  }

  // ---- r = inner + cross: store pre-norm + GroupNorm partials
  float ls = 0.f, lss = 0.f;
  #pragma unroll
  for (int ni = 0; ni < 4; ni++)
    #pragma unroll
    for (int r = 0; r < 4; r++)
      if (rowok[r]){
        float v = acc2[ni][r];
        ls += v; lss += v*v;
        out[(size_t)(b*257 + gi[r])*512 + h*64 + ni*16 + l16] = v;
      }
  #pragma unroll
  for (int m = 1; m < 64; m <<= 1){ ls += __shfl_xor(ls, m, 64); lss += __shfl_xor(lss, m, 64); }
  if (lane == 0){ red[wave*2] = ls; red[wave*2 + 1] = lss; }
  __syncthreads();                                   // (5)
  if (tid == 0){
    partials[((size_t)bh*5 + t)*2 + 0] = red[0] + red[2] + red[4] + red[6];
    partials[((size_t)bh*5 + t)*2 + 1] = red[1] + red[3] + red[5] + red[7];
  }
}

// ---- Kernel D: GroupNorm finalize in place. grid(256) = (b,h) ----
__global__ __launch_bounds__(256) void norm_kernel(const float* __restrict__ partials,
                                                   const float* __restrict__ gnw,
                                                   const float* __restrict__ gnb,
                                                   float* __restrict__ out){
  const int bh = blockIdx.x, b = bh >> 3, h = bh & 7;
  float s = 0.f, s2 = 0.f;
  #pragma unroll
  for (int tt = 0; tt < 5; tt++){
    s  += partials[(bh*5 + tt)*2 + 0];
    s2 += partials[(bh*5 + tt)*2 + 1];
  }
  const float cnt = 257.f * 64.f;
  float mean = s / cnt;
  float var  = s2 / cnt - mean * mean;
  float isd  = rsqrtf(var + 1e-5f);
  float wsc  = gnw[h] * isd;
  float bia  = gnb[h] - mean * wsc;
  for (int idx = threadIdx.x; idx < 257*16; idx += 256){
    int n = idx >> 4, e4 = (idx & 15) * 4;
    size_t off = (size_t)(b*257 + n)*512 + h*64 + e4;
    float4 v = *(float4*)&out[off];
    v.x = v.x * wsc + bia; v.y = v.y * wsc + bia;
    v.z = v.z * wsc + bia; v.w = v.w * wsc + bia;
    *(float4*)&out[off] = v;
  }
}

extern "C" void kernel_launch(void* const* d_in, const int* in_sizes, int n_in,
                              void* d_out, int out_size, void* d_ws, size_t ws_size,
                              hipStream_t stream){
  (void)in_sizes; (void)n_in; (void)out_size; (void)ws_size;
  const float* x   = (const float*)d_in[0];
  const int*   msk = (const int*)d_in[1];
  const float* w   = (const float*)d_in[2];
  const float* pkv = (const float*)d_in[3];
  const float* gnw = (const float*)d_in[4];
  const float* gnb = (const float*)d_in[5];
  float* out = (float*)d_out;

  unsigned short* qkv = (unsigned short*)d_ws;                       // 25264128 B
  unsigned short* xb  = (unsigned short*)((char*)d_ws + 25264128);   // 8421376 B
  unsigned short* wb  = (unsigned short*)((char*)d_ws + 33685504);   // 1572864 B
  float* mnorm    = (float*)((char*)d_ws + 35258368);                // 32768 B
  float* partials = (float*)((char*)d_ws + 35291136);                // 10240 B

  hipLaunchKernelGGL(prep_kernel, dim3(32), dim3(256), 0, stream, msk, mnorm);
  hipLaunchKernelGGL(cvt_kernel, dim3(4880), dim3(256), 0, stream, x, w, xb, wb);
  hipLaunchKernelGGL(qkv_gemm, dim3(12, 65), dim3(256), 0, stream, xb, wb, qkv);
  hipLaunchKernelGGL(retention_kernel, dim3(5, 256), dim3(256), 49440, stream,
                     qkv, pkv, mnorm, out, partials);
  hipLaunchKernelGGL(norm_kernel, dim3(256), dim3(256), 0, stream, partials, gnw, gnb, out);
}